// Round 4
// baseline (115.697 us; speedup 1.0000x reference)
//
#include <hip/hip_runtime.h>

// ContextGuidedTokenShift on MI355X.
// x: (B=8, N=16384, C=576) f32, H=W=128. out = w*shift(x) + (1-w)*x
// Channel slabs (widths all multiples of 16) each have a fixed (dy,dx):
//   c in [0,256):   slab = c>>6            (4 slabs of 64)
//   c in [256,512): slab = 4 + (c-256)>>5  (8 slabs of 32)
//   c in [512,576): slab = 12 + (c-512)>>4 (4 slabs of 16)
// shifted[y,x] = in[y-dy, x-dx] if in bounds else 0.
//
// R4: (a) dy/dx tables as packed 4-bit nibbles in 64-bit immediates -> the
// shifted-load address is pure VALU (no per-lane constant-mem load in the
// dependent chain); (b) 2 float4 per thread (base+t, base+256+t) for 4
// independent loads in flight; (c) keep XCD swizzle + NT streaming stores.

#define B_   8
#define HW_  128
#define N_   16384      // HW_*HW_
#define C_   576
#define C4_  144        // C_/4
#define NXCD 8

typedef float f32x4 __attribute__((ext_vector_type(4)));

// nibble s = (d + 2); dy/dx per slab s in [0,16)
#define DY_PACK 0x0404131304221322ULL
#define DX_PACK 0x4004311322042213ULL

__device__ __forceinline__ void cgts_one(const float* __restrict__ in,
                                         float* __restrict__ out,
                                         int idx, float w, float omw) {
    // decompose flat float4 index -> (b, token, channel4)
    const int c4 = idx % C4_;          // magic-mul division
    const int t  = idx / C4_;          // b*N + n
    const int n  = t & (N_ - 1);
    const int b  = t >> 14;            // N_ = 2^14
    const int y  = n >> 7;             // HW_ = 2^7
    const int xc = n & (HW_ - 1);
    const int c  = c4 << 2;

    // slab index -> offset (pure VALU via packed nibbles)
    int s;
    if (c < 256)      s = c >> 6;
    else if (c < 512) s = 4 + ((c - 256) >> 5);
    else              s = 12 + ((c - 512) >> 4);
    const int sh4 = s << 2;
    const int dy = (int)((DY_PACK >> sh4) & 0xF) - 2;
    const int dx = (int)((DX_PACK >> sh4) & 0xF) - 2;

    // self load: flat float index = 4*idx (contiguous across the block)
    const f32x4 self = *reinterpret_cast<const f32x4*>(in + (size_t)idx * 4);

    const int sy = y - dy;
    const int sx = xc - dx;
    f32x4 sh = (f32x4){0.f, 0.f, 0.f, 0.f};
    if ((unsigned)sy < (unsigned)HW_ && (unsigned)sx < (unsigned)HW_) {
        const size_t sidx = ((size_t)(b * N_ + (sy << 7) + sx)) * C_ + c;
        sh = *reinterpret_cast<const f32x4*>(in + sidx);
    }

    f32x4 o;
    o.x = w * sh.x + omw * self.x;
    o.y = w * sh.y + omw * self.y;
    o.z = w * sh.z + omw * self.z;
    o.w = w * sh.w + omw * self.w;
    // streaming store: output is never re-read; keep L2/L3 for the input
    __builtin_nontemporal_store(o, reinterpret_cast<f32x4*>(out + (size_t)idx * 4));
}

__global__ __launch_bounds__(256) void cgts_kernel(const float* __restrict__ in,
                                                   const float* __restrict__ wptr,
                                                   float* __restrict__ out) {
    // XCD-aware swizzle: hardware dispatches blockIdx round-robin across the
    // 8 XCDs; remap so XCD k processes a contiguous chunk of the index space.
    // grid = 36864 blocks, divisible by 8 -> bijective.
    const int bid = blockIdx.x;
    const int swz = (bid & (NXCD - 1)) * (int)(gridDim.x / NXCD) + (bid >> 3);
    const int base = swz * 512 + (int)threadIdx.x;  // block owns 512 float4

    const float w   = wptr[0];
    const float omw = 1.0f - w;

    cgts_one(in, out, base,       w, omw);
    cgts_one(in, out, base + 256, w, omw);
}

extern "C" void kernel_launch(void* const* d_in, const int* in_sizes, int n_in,
                              void* d_out, int out_size, void* d_ws, size_t ws_size,
                              hipStream_t stream) {
    const float* x = (const float*)d_in[0];
    const float* w = (const float*)d_in[1];
    float* out = (float*)d_out;

    const int total4 = B_ * N_ * C4_;          // 18,874,368 float4 chunks
    const int blocks = total4 / 512;           // 36,864 (exact, divisible by 8)
    cgts_kernel<<<blocks, 256, 0, stream>>>(x, w, out);
}

// Round 5
// 109.194 us; speedup vs baseline: 1.0596x; 1.0596x over previous
//
#include <hip/hip_runtime.h>

// ContextGuidedTokenShift on MI355X.
// x: (B=8, N=16384, C=576) f32, H=W=128. out = w*shift(x) + (1-w)*x
// Channel slabs (widths all multiples of 16) each have a fixed (dy,dx):
//   c in [0,256):   slab = c>>6            (4 slabs of 64)
//   c in [256,512): slab = 4 + (c-256)>>5  (8 slabs of 32)
//   c in [512,576): slab = 12 + (c-512)>>4 (4 slabs of 16)
// shifted[y,x] = in[y-dy, x-dx] if in bounds else 0.
//
// R5: R3 structure (1 float4/thread — R4's 2-per-thread regressed 7%) with
// the single change: dy/dx via packed 4-bit nibbles in 64-bit immediates
// (pure VALU in the shifted-address chain; no per-lane constant-mem load).
// Keep XCD-aware swizzle + NT streaming stores.

#define B_   8
#define HW_  128
#define N_   16384      // HW_*HW_
#define C_   576
#define C4_  144        // C_/4
#define NXCD 8

typedef float f32x4 __attribute__((ext_vector_type(4)));

// nibble s = (d + 2); dy/dx per slab s in [0,16)
#define DY_PACK 0x0404131304221322ULL
#define DX_PACK 0x4004311322042213ULL

__global__ __launch_bounds__(256) void cgts_kernel(const float* __restrict__ in,
                                                   const float* __restrict__ wptr,
                                                   float* __restrict__ out) {
    // XCD-aware swizzle: hardware dispatches blockIdx round-robin across the
    // 8 XCDs; remap so XCD k processes a contiguous chunk of the index space.
    // grid = 73728 blocks, divisible by 8 -> bijective.
    const int bid = blockIdx.x;
    const int swz = (bid & (NXCD - 1)) * (int)(gridDim.x / NXCD) + (bid >> 3);
    const int idx = swz * 256 + (int)threadIdx.x;   // float4 index

    const float w   = wptr[0];
    const float omw = 1.0f - w;

    // decompose flat float4 index -> (b, token, channel4)
    const int c4 = idx % C4_;          // magic-mul division
    const int t  = idx / C4_;          // b*N + n
    const int n  = t & (N_ - 1);
    const int b  = t >> 14;            // N_ = 2^14
    const int y  = n >> 7;             // HW_ = 2^7
    const int xc = n & (HW_ - 1);
    const int c  = c4 << 2;

    // slab index -> offset (pure VALU via packed nibbles)
    int s;
    if (c < 256)      s = c >> 6;
    else if (c < 512) s = 4 + ((c - 256) >> 5);
    else              s = 12 + ((c - 512) >> 4);
    const int sh4 = s << 2;
    const int dy = (int)((DY_PACK >> sh4) & 0xF) - 2;
    const int dx = (int)((DX_PACK >> sh4) & 0xF) - 2;

    // self load: flat float index = 4*idx (contiguous within each XCD chunk)
    const f32x4 self = *reinterpret_cast<const f32x4*>(in + (size_t)idx * 4);

    const int sy = y - dy;
    const int sx = xc - dx;
    f32x4 sh = (f32x4){0.f, 0.f, 0.f, 0.f};
    if ((unsigned)sy < (unsigned)HW_ && (unsigned)sx < (unsigned)HW_) {
        const size_t sidx = ((size_t)(b * N_ + (sy << 7) + sx)) * C_ + c;
        sh = *reinterpret_cast<const f32x4*>(in + sidx);
    }

    f32x4 o;
    o.x = w * sh.x + omw * self.x;
    o.y = w * sh.y + omw * self.y;
    o.z = w * sh.z + omw * self.z;
    o.w = w * sh.w + omw * self.w;
    // streaming store: output is never re-read; keep L2/L3 for the input
    __builtin_nontemporal_store(o, reinterpret_cast<f32x4*>(out + (size_t)idx * 4));
}

extern "C" void kernel_launch(void* const* d_in, const int* in_sizes, int n_in,
                              void* d_out, int out_size, void* d_ws, size_t ws_size,
                              hipStream_t stream) {
    const float* x = (const float*)d_in[0];
    const float* w = (const float*)d_in[1];
    float* out = (float*)d_out;

    const int total4 = B_ * N_ * C4_;          // 18,874,368 float4 chunks
    const int blocks = total4 / 256;           // 73,728 (exact, divisible by 8)
    cgts_kernel<<<blocks, 256, 0, stream>>>(x, w, out);
}